// Round 2
// 537.602 us; speedup vs baseline: 1.2025x; 1.2025x over previous
//
#include <hip/hip_runtime.h>
#include <stdint.h>

#define M_DIM 8192
#define N_DIM 4096
#define K_DIM 4096
#define NW (N_DIM * K_DIM)   // 16777216 weight elements
#define RM_BLOCKS 2048

typedef __bf16 bf16x8 __attribute__((ext_vector_type(8)));
typedef float  floatx4 __attribute__((ext_vector_type(4)));
typedef unsigned short u16;
typedef unsigned int   u32;

// ---------------- stats pass 1: per-block partial sums (no atomics) ----------------
// part aliases the tern region (ws+256): consumed by finalize_stats BEFORE tern_cvt
// overwrites it (stream-ordered). Keeps workspace footprint identical to the
// known-good round-0 layout.
__global__ void reduce_moments(const float* __restrict__ w,
                               const float* __restrict__ msk,
                               double* __restrict__ part) {
    const int nv = NW / 4;
    const int stride = gridDim.x * blockDim.x;
    int idx = blockIdx.x * blockDim.x + threadIdx.x;
    float s1 = 0.f, s2 = 0.f;   // ~8 elems/thread -> fp32 partials fine
    const float4* w4 = (const float4*)w;
    const float4* m4 = (const float4*)msk;
    for (int i = idx; i < nv; i += stride) {
        float4 a = w4[i];
        float4 b = m4[i];
        float p0 = fabsf(a.x * b.x), p1 = fabsf(a.y * b.y);
        float p2 = fabsf(a.z * b.z), p3 = fabsf(a.w * b.w);
        s1 += p0 + p1 + p2 + p3;
        s2 += p0 * p0 + p1 * p1 + p2 * p2 + p3 * p3;
    }
    double d1 = (double)s1, d2 = (double)s2;
    #pragma unroll
    for (int off = 32; off > 0; off >>= 1) {
        d1 += __shfl_down(d1, off);
        d2 += __shfl_down(d2, off);
    }
    __shared__ double sh[8];
    int lane = threadIdx.x & 63;
    int wv = threadIdx.x >> 6;
    if (lane == 0) { sh[wv] = d1; sh[wv + 4] = d2; }
    __syncthreads();
    if (threadIdx.x == 0) {
        part[blockIdx.x]             = sh[0] + sh[1] + sh[2] + sh[3];
        part[RM_BLOCKS + blockIdx.x] = sh[4] + sh[5] + sh[6] + sh[7];
    }
}

// ---------------- stats pass 2: reduce partials, finalize scale/threshold ----------------
__global__ void finalize_stats(const double* __restrict__ part, float* __restrict__ st) {
    double s1 = 0.0, s2 = 0.0;
    for (int i = threadIdx.x; i < RM_BLOCKS; i += 256) {
        s1 += part[i];
        s2 += part[RM_BLOCKS + i];
    }
    #pragma unroll
    for (int off = 32; off > 0; off >>= 1) {
        s1 += __shfl_down(s1, off);
        s2 += __shfl_down(s2, off);
    }
    __shared__ double sh[8];
    int lane = threadIdx.x & 63;
    int wv = threadIdx.x >> 6;
    if (lane == 0) { sh[wv] = s1; sh[wv + 4] = s2; }
    __syncthreads();
    if (threadIdx.x == 0) {
        double S1 = sh[0] + sh[1] + sh[2] + sh[3];
        double S2 = sh[4] + sh[5] + sh[6] + sh[7];
        const double n = (double)NW;
        double mean = S1 / n;
        double var = (S2 - S1 * S1 / n) / (n - 1.0);  // ddof=1
        st[0] = (float)(mean + 1e-8);                 // scale
        st[1] = (float)(0.5 * sqrt(var));             // threshold
    }
}

// ---------------- x: fp32 -> bf16 (RTNE) helper ----------------
__device__ __forceinline__ u16 f2bf(float f) {
    u32 u = __float_as_uint(f);
    u += 0x7FFFu + ((u >> 16) & 1u);
    return (u16)(u >> 16);
}

// ---------------- fused: ternarize weights + convert x (one launch) ----------------
__global__ void tern_cvt(const float* __restrict__ w, const float* __restrict__ msk,
                         const float* __restrict__ st, u16* __restrict__ tw,
                         const float* __restrict__ x, u16* __restrict__ xbf) {
    const int b = blockIdx.x;
    if (b < NW / 2048) {                       // 8192 ternarize blocks
        const float thr = st[1];
        const int i = (b * 256 + threadIdx.x) * 8;
        float4 a0 = *(const float4*)(w + i);
        float4 a1 = *(const float4*)(w + i + 4);
        float4 b0 = *(const float4*)(msk + i);
        float4 b1 = *(const float4*)(msk + i + 4);
        float p[8] = {a0.x * b0.x, a0.y * b0.y, a0.z * b0.z, a0.w * b0.w,
                      a1.x * b1.x, a1.y * b1.y, a1.z * b1.z, a1.w * b1.w};
        union { u16 u[8]; uint4 v; } r;
        #pragma unroll
        for (int j = 0; j < 8; ++j)
            r.u[j] = p[j] > thr ? (u16)0x3F80 : (p[j] < -thr ? (u16)0xBF80 : (u16)0);
        *(uint4*)(tw + i) = r.v;
    } else {                                   // 16384 cvt blocks
        const int i = ((b - NW / 2048) * 256 + threadIdx.x) * 8;
        float4 a0 = *(const float4*)(x + i);
        float4 a1 = *(const float4*)(x + i + 4);
        union { u16 u[8]; uint4 v; } r;
        r.u[0] = f2bf(a0.x); r.u[1] = f2bf(a0.y); r.u[2] = f2bf(a0.z); r.u[3] = f2bf(a0.w);
        r.u[4] = f2bf(a1.x); r.u[5] = f2bf(a1.y); r.u[6] = f2bf(a1.z); r.u[7] = f2bf(a1.w);
        *(uint4*)(xbf + i) = r.v;
    }
}

// ---------------- GEMM: 256x256 tile, BK=64, 8 waves, phase-interleaved pipeline ----
__device__ __forceinline__ void gld16(const __bf16* g, __bf16* l) {
    __builtin_amdgcn_global_load_lds(
        (__attribute__((address_space(1))) void*)g,
        (__attribute__((address_space(3))) void*)l, 16, 0, 0);
}

// LDS map (bf16 elems): A buffers [0,16384)+[16384,32768), B [32768,49152)+[49152,65536).
// Each buffer = 32 subtiles of 16 rows x 32 cols (1024 B), subtile st = (r>>4)*2+(c>>5).
// Within subtile, st_16x32 swizzle: elem = (r&15)*32 + ((c&31) ^ ((r&8)<<1)).
// global_load_lds writes linearly (base + lane*16B), so the per-lane GLOBAL source
// col-chunk is inverse-permuted: lane l fetches col ((l&3)*8) ^ ((l&32)?16:0) of its
// row (rule 21: source permutation == read permutation, both the same involution).

#define BARRIER __builtin_amdgcn_s_barrier()
#define LGK0    asm volatile("s_waitcnt lgkmcnt(0)" ::: "memory")
#define VMC4    asm volatile("s_waitcnt vmcnt(4)" ::: "memory")

#define STAGE_A(ktn, dst)                                           \
    gld16(gA[0] + (ktn) * 64, sh + (dst) + (0 * 8 + wv) * 512);     \
    gld16(gA[1] + (ktn) * 64, sh + (dst) + (1 * 8 + wv) * 512);     \
    gld16(gA[2] + (ktn) * 64, sh + (dst) + (2 * 8 + wv) * 512);     \
    gld16(gA[3] + (ktn) * 64, sh + (dst) + (3 * 8 + wv) * 512);

#define STAGE_BH(ktn, dst, h)                                                   \
    gld16(gB[(h) * 2 + 0] + (ktn) * 64, sh + (dst) + ((h) * 16 + wv * 2 + 0) * 512); \
    gld16(gB[(h) * 2 + 1] + (ktn) * 64, sh + (dst) + ((h) * 16 + wv * 2 + 1) * 512);

#define PHASE(pidx, aCur, STAGE_CODE)                                           \
    {                                                                           \
        bf16x8 af[2][2];                                                        \
        _Pragma("unroll")                                                       \
        for (int mi = 0; mi < 2; ++mi)                                          \
            _Pragma("unroll")                                                   \
            for (int ks = 0; ks < 2; ++ks)                                      \
                af[mi][ks] = *(const bf16x8*)(sh + (aCur) +                     \
                    ((rsA + (pidx) * 2 + mi) * 2 + ks) * 512 + laneElem);       \
        STAGE_CODE                                                              \
        BARRIER;                                                                \
        LGK0;                                                                   \
        __builtin_amdgcn_s_setprio(1);                                          \
        _Pragma("unroll")                                                       \
        for (int mi = 0; mi < 2; ++mi)                                          \
            _Pragma("unroll")                                                   \
            for (int ni = 0; ni < 4; ++ni)                                      \
                _Pragma("unroll")                                               \
                for (int ks = 0; ks < 2; ++ks)                                  \
                    acc[(pidx) * 2 + mi][ni] =                                  \
                        __builtin_amdgcn_mfma_f32_16x16x32_bf16(                \
                            af[mi][ks], bfr[ni][ks], acc[(pidx) * 2 + mi][ni],  \
                            0, 0, 0);                                           \
        __builtin_amdgcn_s_setprio(0);                                          \
    }

#define TILE(P, kt)                                                             \
    {                                                                           \
        const int aCur = (P) * 16384;                                           \
        const int aNxt = ((P) ^ 1) * 16384;                                     \
        const int bCur = 32768 + (P) * 16384;                                   \
        const int kt1 = ((kt) + 1) & 63;                                        \
        const int kt2 = ((kt) + 2) & 63;                                        \
        _Pragma("unroll")                                                       \
        for (int ni = 0; ni < 4; ++ni)                                          \
            _Pragma("unroll")                                                   \
            for (int ks = 0; ks < 2; ++ks)                                      \
                bfr[ni][ks] = *(const bf16x8*)(sh + bCur +                      \
                    ((rsB + ni) * 2 + ks) * 512 + laneElem);                    \
        PHASE(0, aCur, STAGE_A(kt1, aNxt))                                      \
        BARRIER;                                                                \
        PHASE(1, aCur, STAGE_BH(kt2, bCur, 0))                                  \
        BARRIER;                                                                \
        PHASE(2, aCur, STAGE_BH(kt2, bCur, 1))                                  \
        BARRIER;                                                                \
        PHASE(3, aCur, ;)                                                       \
        VMC4;                                                                   \
        BARRIER;                                                                \
    }

__global__ __launch_bounds__(512, 2) void gemm_tern(
        const __bf16* __restrict__ A, const __bf16* __restrict__ B,
        const float* __restrict__ bias, const float* __restrict__ st,
        float* __restrict__ C) {
    __shared__ __bf16 sh[65536];   // 128 KiB

    const int t = threadIdx.x;
    const int lane = t & 63;
    const int wv = t >> 6;              // 8 waves: 2 (M) x 4 (N)
    const int wm = (wv >> 2) * 128;     // wave row offset in 256x256 tile
    const int wn = (wv & 3) * 64;       // wave col offset
    const int bm = blockIdx.y * 256;
    const int bn = blockIdx.x * 256;

    // swizzled LDS read offset within a subtile (elems): row = lane&15,
    // col = ((lane>>4)*8) ^ (row&8 ? 16 : 0)
    const int laneElem = ((lane & 15) << 5) +
                         (((lane >> 4) << 3) ^ ((lane & 8) << 1));
    const int rsA = wm >> 4;            // 0 or 8
    const int rsB = wn >> 4;            // 0,4,8,12

    // staging: inverse-permuted per-lane global source (same involution as read)
    const int lp = lane ^ ((lane & 32) >> 4);
    const int srow = lp >> 2;           // row within 16-row subtile (== lane>>2)
    const int scol = (lp & 3) * 8;      // col chunk within 32-col subtile

    const __bf16* gA[4];
    #pragma unroll
    for (int i = 0; i < 4; ++i) {
        int stA = i * 8 + wv;           // subtile index 0..31
        gA[i] = A + (size_t)(bm + (stA >> 1) * 16 + srow) * K_DIM +
                (stA & 1) * 32 + scol;
    }
    const __bf16* gB[4];
    #pragma unroll
    for (int j = 0; j < 2; ++j) {
        int st0 = wv * 2 + j;           // half 0: rows 0-127 (subtiles 0-15)
        gB[j] = B + (size_t)(bn + (st0 >> 1) * 16 + srow) * K_DIM +
                (st0 & 1) * 32 + scol;
        int st1 = 16 + wv * 2 + j;      // half 1: rows 128-255 (subtiles 16-31)
        gB[2 + j] = B + (size_t)(bn + (st1 >> 1) * 16 + srow) * K_DIM +
                    (st1 & 1) * 32 + scol;
    }

    floatx4 acc[8][4] = {};
    bf16x8 bfr[4][2];

    // prologue: stage A(0)->Abuf0, B(0)->Bbuf0, B(1)->Bbuf1; keep B(1) in flight
    STAGE_A(0, 0)
    STAGE_BH(0, 32768, 0)
    STAGE_BH(0, 32768, 1)
    STAGE_BH(1, 32768 + 16384, 0)
    STAGE_BH(1, 32768 + 16384, 1)
    VMC4;        // A(0)+B(0) landed; B(1)'s 4 loads may remain in flight
    BARRIER;

    #pragma unroll 1
    for (int t2 = 0; t2 < 64; t2 += 2) {
        TILE(0, t2)
        TILE(1, t2 + 1)
    }

    // epilogue: D layout col=lane&15, row=(lane>>4)*4+reg (m89/m91-verified)
    const float scale = st[0];
    const int rbase = bm + wm + ((lane >> 4) << 2);
    const int cbase = bn + wn + (lane & 15);
    #pragma unroll
    for (int ni = 0; ni < 4; ++ni) {
        const int col = cbase + ni * 16;
        const float bv = bias[col];
        #pragma unroll
        for (int mi = 0; mi < 8; ++mi) {
            const int row = rbase + mi * 16;
            #pragma unroll
            for (int rg = 0; rg < 4; ++rg)
                C[(size_t)(row + rg) * N_DIM + col] = acc[mi][ni][rg] * scale + bv;
        }
    }
}

// ---------------- launcher ----------------
extern "C" void kernel_launch(void* const* d_in, const int* in_sizes, int n_in,
                              void* d_out, int out_size, void* d_ws, size_t ws_size,
                              hipStream_t stream) {
    const float* x    = (const float*)d_in[0];   // [8192,4096]
    const float* w    = (const float*)d_in[1];   // [4096,4096]
    const float* msk  = (const float*)d_in[2];   // [4096,4096]
    const float* bias = (const float*)d_in[3];   // [4096]
    float* out = (float*)d_out;                  // [8192,4096]

    // Workspace layout IDENTICAL footprint to the verified round-0 kernel:
    //   [64,72)    st (scale, threshold)
    //   [256, 256+32MB)  tern  — ALIASED with moments partials (32 KB), which are
    //                            fully consumed by finalize_stats before tern_cvt runs
    //   [256+32MB, 256+96MB) xbf
    char* ws = (char*)d_ws;
    float*  st   = (float*)(ws + 64);
    double* part = (double*)(ws + 256);                     // 32 KB, aliases tern
    u16*    tern = (u16*)(ws + 256);                        // 32 MB ternary weights
    u16*    xbf  = (u16*)(ws + 256 + (size_t)NW * 2);       // 64 MB x in bf16

    reduce_moments<<<RM_BLOCKS, 256, 0, stream>>>(w, msk, part);
    finalize_stats<<<1, 256, 0, stream>>>(part, st);
    tern_cvt<<<NW / 2048 + (M_DIM * K_DIM) / 2048, 256, 0, stream>>>(
        w, msk, st, tern, x, xbf);

    dim3 grid(N_DIM / 256, M_DIM / 256);   // 16 x 32 tiles
    gemm_tern<<<grid, 512, 0, stream>>>((const __bf16*)xbf, (const __bf16*)tern,
                                        bias, st, out);
}